// Round 2
// baseline (299.462 us; speedup 1.0000x reference)
//
#include <hip/hip_runtime.h>
#include <hip/hip_cooperative_groups.h>

namespace cg = cooperative_groups;

// IPC point-edge barrier energy, MI355X — single fused cooperative kernel.
// Inputs (setup_inputs order):
//   d_in[0] Uu              float32 [N_VERTS*2]
//   d_in[1] rest_positions  float32 [N_VERTS*2]
//   d_in[2] pair_v          int32   [N_PAIRS]
//   d_in[3] pair_e0         int32   [N_PAIRS]
//   d_in[4] pair_e1         int32   [N_PAIRS]
// Output: scalar float32 barrier energy.
//
// R2 change: collapse {coords_k, hipMemsetAsync, pairs_k} (3 dispatch nodes,
// ~90us of inter-dispatch gap in the replayed graph) into ONE cooperative
// kernel: phase A builds coords + zeroes out, grid.sync(), phase B gathers.
// The gather phase itself is at a divergent-gather throughput wall
// (~0.35 line-probes/cy/CU, insensitive to occupancy/NT/scheduling — R0/R1
// evidence), so the win targeted here is dispatch overhead, not the gather.

constexpr int N_VERTS = 262144;
constexpr int N_PAIRS = 8388608;
constexpr float DHAT2 = 0.05f * 0.05f;       // 0.0025
constexpr float INV_DHAT2 = 1.0f / DHAT2;    // 400
constexpr float EPSF = 1e-12f;

using i32x4 = __attribute__((ext_vector_type(4))) int;
using f32x4 = __attribute__((ext_vector_type(4))) float;

__global__ __launch_bounds__(256) void fused_k(
    const f32x4* __restrict__ Uu,
    const f32x4* __restrict__ rest,
    f32x4* __restrict__ coords4,
    const i32x4* __restrict__ pv,
    const i32x4* __restrict__ pe0,
    const i32x4* __restrict__ pe1,
    float* __restrict__ out,
    int out_n)
{
    const int tid = blockIdx.x * blockDim.x + threadIdx.x;
    const int nthreads = gridDim.x * blockDim.x;

    // ---- phase A: coords = rest + Uu (131072 float4 elements); zero out ----
    constexpr int NV4 = (N_VERTS * 2) / 4;
    for (int i = tid; i < NV4; i += nthreads) {
        f32x4 u = __builtin_nontemporal_load(&Uu[i]);
        f32x4 r = __builtin_nontemporal_load(&rest[i]);
        coords4[i] = u + r;   // normal store: keep coords cached in L2
    }
    if (tid < out_n) out[tid] = 0.0f;

    cg::this_grid().sync();   // device-scope barrier + memory visibility

    // ---- phase B: per-pair barrier energy ----
    const float2* __restrict__ coords = (const float2*)coords4;
    float acc = 0.0f;
    constexpr int NQUADS = N_PAIRS / 4;

    for (int q = tid; q < NQUADS; q += nthreads) {
        i32x4 v4 = __builtin_nontemporal_load(&pv[q]);
        i32x4 a4 = __builtin_nontemporal_load(&pe0[q]);
        i32x4 b4 = __builtin_nontemporal_load(&pe1[q]);

#pragma unroll
        for (int k = 0; k < 4; ++k) {
            float2 p = coords[v4[k]];
            float2 a = coords[a4[k]];
            float2 b = coords[b4[k]];

            float abx = b.x - a.x, aby = b.y - a.y;
            float apx = p.x - a.x, apy = p.y - a.y;

            float denom = fmaxf(abx * abx + aby * aby, EPSF);
            float t = (apx * abx + apy * aby) / denom;
            t = fminf(fmaxf(t, 0.0f), 1.0f);

            float dx = apx - t * abx;
            float dy = apy - t * aby;
            float d2 = dx * dx + dy * dy;

            float d2s = fmaxf(d2, EPSF);
            float dm = d2s - DHAT2;
            float term = -(dm * dm) * __logf(d2s * INV_DHAT2);
            acc += (d2 < DHAT2) ? term : 0.0f;
        }
    }

    // wave (64-lane) shuffle reduction
#pragma unroll
    for (int off = 32; off > 0; off >>= 1)
        acc += __shfl_down(acc, off, 64);

    __shared__ float wsum[4];  // 256 threads = 4 waves
    int lane = threadIdx.x & 63;
    int wave = threadIdx.x >> 6;
    if (lane == 0) wsum[wave] = acc;
    __syncthreads();

    if (threadIdx.x == 0) {
        float s = wsum[0] + wsum[1] + wsum[2] + wsum[3];
        atomicAdd(out, s);
    }
}

// ---------------------------------------------------------------------------
extern "C" void kernel_launch(void* const* d_in, const int* in_sizes, int n_in,
                              void* d_out, int out_size, void* d_ws, size_t ws_size,
                              hipStream_t stream) {
    const f32x4* Uu   = (const f32x4*)d_in[0];
    const f32x4* rest = (const f32x4*)d_in[1];
    const i32x4* pv   = (const i32x4*)d_in[2];
    const i32x4* pe0  = (const i32x4*)d_in[3];
    const i32x4* pe1  = (const i32x4*)d_in[4];
    float* out = (float*)d_out;

    f32x4* coords4 = (f32x4*)d_ws;  // 2 MB: N_VERTS * 2 floats
    int out_n = out_size;

    // grid must be fully co-resident for cooperative launch:
    // query blocks/CU once (VGPR~30 @256 thr -> expect 8/CU -> 2048 blocks).
    static int blocks = 0;
    if (blocks == 0) {
        int per_cu = 0;
        if (hipOccupancyMaxActiveBlocksPerMultiprocessor(&per_cu, fused_k, 256, 0)
                != hipSuccess || per_cu <= 0)
            per_cu = 8;
        blocks = per_cu * 256;           // 256 CUs
        if (blocks > 2048) blocks = 2048;
        if (blocks < 256)  blocks = 256;
    }

    void* args[] = {(void*)&Uu, (void*)&rest, (void*)&coords4,
                    (void*)&pv, (void*)&pe0, (void*)&pe1,
                    (void*)&out, (void*)&out_n};
    hipLaunchCooperativeKernel((const void*)fused_k, dim3(blocks), dim3(256),
                               args, 0, stream);
}

// Round 4
// 228.641 us; speedup vs baseline: 1.3097x; 1.3097x over previous
//
#include <hip/hip_runtime.h>

// IPC point-edge barrier energy, MI355X.
// Inputs (setup_inputs order):
//   d_in[0] Uu              float32 [N_VERTS*2]
//   d_in[1] rest_positions  float32 [N_VERTS*2]
//   d_in[2] pair_v          int32   [N_PAIRS]
//   d_in[3] pair_e0         int32   [N_PAIRS]
//   d_in[4] pair_e1         int32   [N_PAIRS]
// Output: scalar float32 barrier energy.
//
// R4 = R3 + the rule-#18 correctness fence: hipcc hoists register-only
// consumers past an inline-asm s_waitcnt even with a "memory" clobber, so
// the batched-gather wait needs __builtin_amdgcn_sched_barrier(0) right
// after it. Experiment under test (unchanged): sc0 gathers (bypass L1
// allocation, serve from L2) -> does the 2.9 cyc/divergent-address service
// rate drop toward the ~1 line/cy TA floor?

constexpr int N_VERTS = 262144;
constexpr int N_PAIRS = 8388608;
constexpr float DHAT2 = 0.05f * 0.05f;       // 0.0025
constexpr float INV_DHAT2 = 1.0f / DHAT2;    // 400
constexpr float EPSF = 1e-12f;

using i32x4 = __attribute__((ext_vector_type(4))) int;
using f32x2 = __attribute__((ext_vector_type(2))) float;
using f32x4 = __attribute__((ext_vector_type(4))) float;

// ---------------------------------------------------------------------------
// Kernel A: coords = rest + Uu (131072 float4) + zero the output accumulator.
// ---------------------------------------------------------------------------
__global__ __launch_bounds__(256) void coords_k(const f32x4* __restrict__ Uu,
                                                const f32x4* __restrict__ rest,
                                                f32x4* __restrict__ coords,
                                                float* __restrict__ out,
                                                int out_n) {
    int i = blockIdx.x * blockDim.x + threadIdx.x;
    f32x4 u = Uu[i];
    f32x4 r = rest[i];
    coords[i] = u + r;
    if (i < out_n) out[i] = 0.0f;
}

// ---------------------------------------------------------------------------
// Kernel B: per-pair barrier + reduction.
// ---------------------------------------------------------------------------
__global__ __launch_bounds__(256) void pairs_k(const f32x2* __restrict__ coords,
                                               const i32x4* __restrict__ pv,
                                               const i32x4* __restrict__ pe0,
                                               const i32x4* __restrict__ pe1,
                                               float* __restrict__ out) {
    float acc = 0.0f;
    const int nquads = N_PAIRS / 4;
    const int stride = gridDim.x * blockDim.x;

    for (int q = blockIdx.x * blockDim.x + threadIdx.x; q < nquads; q += stride) {
        i32x4 v4 = __builtin_nontemporal_load(&pv[q]);
        i32x4 a4 = __builtin_nontemporal_load(&pe0[q]);
        i32x4 b4 = __builtin_nontemporal_load(&pe1[q]);

        // Batch all 12 gathers with sc0 (no L1 allocation; L2-direct), one
        // vmcnt(0), then a sched_barrier(0) fence so the compiler cannot
        // hoist the register-only consumers above the wait (rule #18).
        f32x2 P[4], A[4], B[4];
        __builtin_amdgcn_sched_barrier(0);
#pragma unroll
        for (int k = 0; k < 4; ++k) {
            const f32x2* pp = coords + v4[k];
            const f32x2* pa = coords + a4[k];
            const f32x2* pb = coords + b4[k];
            asm volatile("global_load_dwordx2 %0, %1, off sc0"
                         : "=&v"(P[k]) : "v"(pp));
            asm volatile("global_load_dwordx2 %0, %1, off sc0"
                         : "=&v"(A[k]) : "v"(pa));
            asm volatile("global_load_dwordx2 %0, %1, off sc0"
                         : "=&v"(B[k]) : "v"(pb));
        }
        asm volatile("s_waitcnt vmcnt(0)" ::: "memory");
        __builtin_amdgcn_sched_barrier(0);

#pragma unroll
        for (int k = 0; k < 4; ++k) {
            float px = P[k].x, py = P[k].y;
            float ax = A[k].x, ay = A[k].y;
            float bx = B[k].x, by = B[k].y;

            float abx = bx - ax, aby = by - ay;
            float apx = px - ax, apy = py - ay;

            float denom = fmaxf(abx * abx + aby * aby, EPSF);
            float t = (apx * abx + apy * aby) / denom;
            t = fminf(fmaxf(t, 0.0f), 1.0f);

            float dx = apx - t * abx;
            float dy = apy - t * aby;
            float d2 = dx * dx + dy * dy;

            float d2s = fmaxf(d2, EPSF);
            float dm = d2s - DHAT2;
            float term = -(dm * dm) * __logf(d2s * INV_DHAT2);
            acc += (d2 < DHAT2) ? term : 0.0f;
        }
    }

    // wave (64-lane) shuffle reduction
#pragma unroll
    for (int off = 32; off > 0; off >>= 1)
        acc += __shfl_down(acc, off, 64);

    __shared__ float wsum[4];  // 256 threads = 4 waves
    int lane = threadIdx.x & 63;
    int wave = threadIdx.x >> 6;
    if (lane == 0) wsum[wave] = acc;
    __syncthreads();

    if (threadIdx.x == 0) {
        float s = wsum[0] + wsum[1] + wsum[2] + wsum[3];
        atomicAdd(out, s);
    }
}

// ---------------------------------------------------------------------------
extern "C" void kernel_launch(void* const* d_in, const int* in_sizes, int n_in,
                              void* d_out, int out_size, void* d_ws, size_t ws_size,
                              hipStream_t stream) {
    const f32x4* Uu   = (const f32x4*)d_in[0];
    const f32x4* rest = (const f32x4*)d_in[1];
    const i32x4* pv   = (const i32x4*)d_in[2];
    const i32x4* pe0  = (const i32x4*)d_in[3];
    const i32x4* pe1  = (const i32x4*)d_in[4];
    float* out = (float*)d_out;

    f32x2* coords = (f32x2*)d_ws;  // 2 MB: N_VERTS * 2 floats

    // coords = rest + Uu, and zero the accumulator (d_out poisoned per replay)
    {
        int nvec = (N_VERTS * 2) / 4;  // 131072
        coords_k<<<nvec / 256, 256, 0, stream>>>(
            Uu, rest, (f32x4*)coords, out, out_size);
    }

    // barrier energy
    {
        int blocks = 2048;  // 8 blocks/CU; one atomic per block
        pairs_k<<<blocks, 256, 0, stream>>>(coords, pv, pe0, pe1, out);
    }
}

// Round 5
// 225.543 us; speedup vs baseline: 1.3277x; 1.0137x over previous
//
#include <hip/hip_runtime.h>

// IPC point-edge barrier energy, MI355X.
// Inputs (setup_inputs order):
//   d_in[0] Uu              float32 [N_VERTS*2]
//   d_in[1] rest_positions  float32 [N_VERTS*2]
//   d_in[2] pair_v          int32   [N_PAIRS]
//   d_in[3] pair_e0         int32   [N_PAIRS]
//   d_in[4] pair_e1         int32   [N_PAIRS]
// Output: scalar float32 barrier energy.
//
// R5: reversion-polish to the measured-best configuration.
//  - pairs_k: compiler-scheduled plain gathers (R0/R1 body). R4's inline-asm
//    sc0 batch + sched_barrier fences were -5us (blocked cross-iteration ILP)
//    and the L1-bypass theory it tested was null.
//  - coords_k: keeps R4's folding of the output-zeroing (memset dispatch gone).
// Bottleneck evidence (R0-R4): 25.2M divergent gathers at ~3.0 cy/request/CU
// = TCP per-miss service floor. Insensitive to occupancy (54/67/73%), sc0,
// NT hints, batching. Request count is fixed by problem structure (random
// indices, ~6% intra-wave line overlap). This is the wall.

constexpr int N_VERTS = 262144;
constexpr int N_PAIRS = 8388608;
constexpr float DHAT2 = 0.05f * 0.05f;       // 0.0025
constexpr float INV_DHAT2 = 1.0f / DHAT2;    // 400
constexpr float EPSF = 1e-12f;

using i32x4 = __attribute__((ext_vector_type(4))) int;
using f32x4 = __attribute__((ext_vector_type(4))) float;

// ---------------------------------------------------------------------------
// Kernel A: coords = rest + Uu (131072 float4) + zero the output accumulator.
// ---------------------------------------------------------------------------
__global__ __launch_bounds__(256) void coords_k(const f32x4* __restrict__ Uu,
                                                const f32x4* __restrict__ rest,
                                                f32x4* __restrict__ coords,
                                                float* __restrict__ out,
                                                int out_n) {
    int i = blockIdx.x * blockDim.x + threadIdx.x;
    f32x4 u = Uu[i];
    f32x4 r = rest[i];
    coords[i] = u + r;
    if (i < out_n) out[i] = 0.0f;
}

// ---------------------------------------------------------------------------
// Kernel B: per-pair barrier + reduction (compiler-scheduled gathers).
// ---------------------------------------------------------------------------
constexpr int BLOCKS = 2048;
constexpr int THREADS = 256;
constexpr int STRIDE = BLOCKS * THREADS;            // 524288
constexpr int NQUADS = N_PAIRS / 4;                 // 2097152
constexpr int QPT = NQUADS / STRIDE;                // exactly 4 quads/thread
static_assert(NQUADS == STRIDE * QPT, "exact division");

__global__ __launch_bounds__(256) void pairs_k(const float2* __restrict__ coords,
                                               const i32x4* __restrict__ pv,
                                               const i32x4* __restrict__ pe0,
                                               const i32x4* __restrict__ pe1,
                                               float* __restrict__ out) {
    float acc = 0.0f;
    const int q0 = blockIdx.x * THREADS + threadIdx.x;

#pragma unroll
    for (int j = 0; j < QPT; ++j) {
        const int q = q0 + j * STRIDE;

        i32x4 v4 = __builtin_nontemporal_load(&pv[q]);
        i32x4 a4 = __builtin_nontemporal_load(&pe0[q]);
        i32x4 b4 = __builtin_nontemporal_load(&pe1[q]);

#pragma unroll
        for (int k = 0; k < 4; ++k) {
            float2 p = coords[v4[k]];
            float2 a = coords[a4[k]];
            float2 b = coords[b4[k]];

            float abx = b.x - a.x, aby = b.y - a.y;
            float apx = p.x - a.x, apy = p.y - a.y;

            float denom = fmaxf(abx * abx + aby * aby, EPSF);
            float t = (apx * abx + apy * aby) / denom;
            t = fminf(fmaxf(t, 0.0f), 1.0f);

            float dx = apx - t * abx;
            float dy = apy - t * aby;
            float d2 = dx * dx + dy * dy;

            float d2s = fmaxf(d2, EPSF);
            float dm = d2s - DHAT2;
            float term = -(dm * dm) * __logf(d2s * INV_DHAT2);
            acc += (d2 < DHAT2) ? term : 0.0f;
        }
    }

    // wave (64-lane) shuffle reduction
#pragma unroll
    for (int off = 32; off > 0; off >>= 1)
        acc += __shfl_down(acc, off, 64);

    __shared__ float wsum[4];  // 256 threads = 4 waves
    int lane = threadIdx.x & 63;
    int wave = threadIdx.x >> 6;
    if (lane == 0) wsum[wave] = acc;
    __syncthreads();

    if (threadIdx.x == 0) {
        float s = wsum[0] + wsum[1] + wsum[2] + wsum[3];
        atomicAdd(out, s);
    }
}

// ---------------------------------------------------------------------------
extern "C" void kernel_launch(void* const* d_in, const int* in_sizes, int n_in,
                              void* d_out, int out_size, void* d_ws, size_t ws_size,
                              hipStream_t stream) {
    const f32x4* Uu   = (const f32x4*)d_in[0];
    const f32x4* rest = (const f32x4*)d_in[1];
    const i32x4* pv   = (const i32x4*)d_in[2];
    const i32x4* pe0  = (const i32x4*)d_in[3];
    const i32x4* pe1  = (const i32x4*)d_in[4];
    float* out = (float*)d_out;

    float2* coords = (float2*)d_ws;  // 2 MB: N_VERTS * 2 floats

    // coords = rest + Uu, and zero the accumulator (d_out poisoned per replay)
    {
        int nvec = (N_VERTS * 2) / 4;  // 131072
        coords_k<<<nvec / 256, 256, 0, stream>>>(
            Uu, rest, (f32x4*)coords, out, out_size);
    }

    // barrier energy
    pairs_k<<<BLOCKS, THREADS, 0, stream>>>(coords, pv, pe0, pe1, out);
}